// Round 13
// baseline (762.372 us; speedup 1.0000x reference)
//
#include <hip/hip_runtime.h>
#include <hip/hip_bf16.h>

typedef unsigned short u16;
typedef unsigned int u32;
typedef unsigned long long u64;
typedef __attribute__((ext_vector_type(8))) _Float16 half8;
typedef __attribute__((ext_vector_type(8))) short short8;
typedef __attribute__((ext_vector_type(4))) float f32x4;
typedef __attribute__((ext_vector_type(16))) float f32x16;
typedef __attribute__((ext_vector_type(4))) int int4v;

#define DEVI __device__ __forceinline__

static constexpr int TOK = 4096;     // B*T
static constexpr int CCD = 1024;     // C
static constexpr int HIDD = 4096;    // 4C

DEVI u16 f2bf(float f) {             // RNE float->bf16 (finite inputs)
  u32 u = __builtin_bit_cast(u32, f);
  u32 r = (u + 0x7fffu + ((u >> 16) & 1u)) >> 16;
  return (u16)r;
}
DEVI float bf2f(u16 v) { u32 u = ((u32)v) << 16; return __builtin_bit_cast(float, u); }
DEVI u32 pkh2(_Float16 a, _Float16 b) {
  u16 ua = __builtin_bit_cast(u16, a), ub = __builtin_bit_cast(u16, b);
  return (u32)ua | ((u32)ub << 16);
}
union H8U { u32 u[4]; half8 h; };
DEVI f32x16 zero16() { f32x16 z;
#pragma unroll
  for (int i = 0; i < 16; ++i) z[i] = 0.f;
  return z; }
DEVI f32x4 zero4() { f32x4 z;
#pragma unroll
  for (int i = 0; i < 4; ++i) z[i] = 0.f;
  return z; }

// async global->LDS, 16B per lane. LDS dest = wave-uniform base + lane*16 (linear).
DEVI void gload16(const void* g, void* l) {
  __builtin_amdgcn_global_load_lds(
      (const __attribute__((address_space(1))) void*)g,
      (__attribute__((address_space(3))) void*)l, 16, 0, 0);
}

// ---------------- cast x -> fp16 hi/lo ----------------
__global__ __launch_bounds__(256) void cast_split_kernel(
    const float* __restrict__ x, _Float16* __restrict__ xh, _Float16* __restrict__ xl) {
  int i = blockIdx.x * 256 + threadIdx.x;      // i indexes float4
  float4 v = ((const float4*)x)[i];
  _Float16 h0 = (_Float16)v.x, h1 = (_Float16)v.y, h2 = (_Float16)v.z, h3 = (_Float16)v.w;
  _Float16 l0 = (_Float16)(v.x - (float)h0), l1 = (_Float16)(v.y - (float)h1);
  _Float16 l2 = (_Float16)(v.z - (float)h2), l3 = (_Float16)(v.w - (float)h3);
  ((uint2*)xh)[i] = make_uint2(pkh2(h0, h1), pkh2(h2, h3));
  ((uint2*)xl)[i] = make_uint2(pkh2(l0, l1), pkh2(l2, l3));
}

// ---------------- transpose fp32 [K][N] -> fp16 split [N][K] ----------------
__global__ __launch_bounds__(256) void trans_split_kernel(
    const float* __restrict__ in, _Float16* __restrict__ oh, _Float16* __restrict__ ol,
    int K, int N) {
  __shared__ float tile[32][33];
  int k0 = blockIdx.x * 32, n0 = blockIdx.y * 32;
  int tx = threadIdx.x & 31, ty = threadIdx.x >> 5;   // ty 0..7
#pragma unroll
  for (int i = 0; i < 4; ++i) { int r = ty + i * 8; tile[r][tx] = in[(size_t)(k0 + r) * N + n0 + tx]; }
  __syncthreads();
#pragma unroll
  for (int i = 0; i < 4; ++i) {
    int r = ty + i * 8;
    float v = tile[tx][r];                    // = in[k0+tx][n0+r]
    _Float16 h = (_Float16)v;
    oh[(size_t)(n0 + r) * K + k0 + tx] = h;
    ol[(size_t)(n0 + r) * K + k0 + tx] = (_Float16)(v - (float)h);
  }
}

// ---------------- transpose fp32 [K][N] -> bf16 [N][K], 64Kx32N tiles, 16B stores ----------------
__global__ __launch_bounds__(256) void trans_bf16_kernel(
    const float* __restrict__ in, u16* __restrict__ ob, int K, int N) {
  __shared__ float tile[64][33];
  in += (size_t)blockIdx.z * K * N;
  ob += (size_t)blockIdx.z * K * N;
  int k0 = blockIdx.x * 64, n0 = blockIdx.y * 32;
  int tx = threadIdx.x & 31, ty = threadIdx.x >> 5;   // ty 0..7
#pragma unroll
  for (int i = 0; i < 8; ++i) {
    int k = ty + i * 8;
    tile[k][tx] = in[(size_t)(k0 + k) * N + n0 + tx];
  }
  __syncthreads();
  int n = threadIdx.x >> 3, kc = (threadIdx.x & 7) * 8;
  short8 sv;
#pragma unroll
  for (int j = 0; j < 8; ++j) sv[j] = (short)f2bf(tile[kc + j][n]);
  *(short8*)(ob + (size_t)(n0 + n) * K + k0 + kc) = sv;
}

// ---------------- transpose V fp16 [bh][1024][64] -> [bh][64][1024], 16B stores ----------------
__global__ __launch_bounds__(256) void vtrans_kernel(
    const _Float16* __restrict__ vh, const _Float16* __restrict__ vl,
    _Float16* __restrict__ vth, _Float16* __restrict__ vtl) {
  __shared__ u32 t0[64][17], t1[64][17];
  size_t base = (size_t)blockIdx.z * 65536;
  int r0 = blockIdx.x * 64;   // t
  int c0 = blockIdx.y * 32;   // d
  int tx = threadIdx.x & 15, ty = threadIdx.x >> 4;   // ty 0..15
#pragma unroll
  for (int i = 0; i < 4; ++i) {
    int t = ty + i * 16;
    t0[t][tx] = *(const u32*)(vh + base + (size_t)(r0 + t) * 64 + c0 + tx * 2);
    t1[t][tx] = *(const u32*)(vl + base + (size_t)(r0 + t) * 64 + c0 + tx * 2);
  }
  __syncthreads();
  int d = threadIdx.x >> 3, tc = (threadIdx.x & 7) * 8;
  short8 sa, sb;
#pragma unroll
  for (int j = 0; j < 8; ++j) {
    u32 w0 = t0[tc + j][d >> 1], w1 = t1[tc + j][d >> 1];
    sa[j] = (short)((d & 1) ? (w0 >> 16) : (w0 & 0xffffu));
    sb[j] = (short)((d & 1) ? (w1 >> 16) : (w1 & 0xffffu));
  }
  size_t dst = base + (size_t)(c0 + d) * 1024 + r0 + tc;
  *(short8*)((u16*)vth + dst) = sa;
  *(short8*)((u16*)vtl + dst) = sb;
}

// ---------------- fp16x3 GEMM, 512 threads (8 waves, 2x4), 128x128 tile, BK=32 ----------------
// dbuf gload_lds (counted vmcnt(4)), pre-swizzled source -> conflict-free XOR reads.
// EPI 0: QKV scatter epilogue; EPI 1: fp32 out + bias0
template <int EPI>
__global__ __launch_bounds__(512, 4) void gemm_f16x3_kernel(
    const _Float16* __restrict__ Ah, const _Float16* __restrict__ Al,
    const _Float16* __restrict__ Bh, const _Float16* __restrict__ Bl,
    const float* __restrict__ bias0, const float* __restrict__ bias1, const float* __restrict__ bias2,
    _Float16* __restrict__ q_h, _Float16* __restrict__ q_l,
    _Float16* __restrict__ k_h, _Float16* __restrict__ k_l,
    _Float16* __restrict__ v_h, _Float16* __restrict__ v_l,
    float* __restrict__ outf, int M, int N, int K) {
  __shared__ __align__(16) _Float16 sA[2][128 * 64];
  __shared__ __align__(16) _Float16 sB[2][128 * 64];
  const int tid = threadIdx.x;
  const int mt = blockIdx.x, nt = blockIdx.y;
  const int lane = tid & 63, wv = tid >> 6;
  const int wm = wv >> 2, wn = wv & 3;         // wave tile 64x32
  f32x4 acc[4][2];
#pragma unroll
  for (int m = 0; m < 4; ++m)
#pragma unroll
    for (int n = 0; n < 2; ++n) acc[m][n] = zero4();

  // slot flat -> (row, sigma); sigma holds data chunk s = sigma ^ (row&7): g=s>>1, hl=s&1
  const _Float16* aS[2]; const _Float16* bS[2];
#pragma unroll
  for (int j = 0; j < 2; ++j) {
    int flat = j * 512 + tid;
    int row = flat >> 3, sg = flat & 7, s = sg ^ (row & 7), g = s >> 1, hl = s & 1;
    aS[j] = (hl ? Al : Ah) + (size_t)(mt * 128 + row) * K + g * 8;
    bS[j] = (hl ? Bl : Bh) + (size_t)(nt * 128 + row) * K + g * 8;
  }

  const int nkt = K >> 5;
#pragma unroll
  for (int j = 0; j < 2; ++j) gload16(aS[j], (char*)sA[0] + (j * 512 + tid) * 16);
#pragma unroll
  for (int j = 0; j < 2; ++j) gload16(bS[j], (char*)sB[0] + (j * 512 + tid) * 16);

  for (int kt = 0; kt < nkt; ++kt) {
    const int cur = kt & 1;
    if (kt + 1 < nkt) {
#pragma unroll
      for (int j = 0; j < 2; ++j) gload16(aS[j] + (kt + 1) * 32, (char*)sA[cur ^ 1] + (j * 512 + tid) * 16);
#pragma unroll
      for (int j = 0; j < 2; ++j) gload16(bS[j] + (kt + 1) * 32, (char*)sB[cur ^ 1] + (j * 512 + tid) * 16);
      asm volatile("s_waitcnt vmcnt(4)" ::: "memory");
    } else {
      asm volatile("s_waitcnt vmcnt(0)" ::: "memory");
    }
    __builtin_amdgcn_s_barrier();
    const int g2 = (lane >> 4) << 1;
    half8 bhf[2], blf[2];
#pragma unroll
    for (int n = 0; n < 2; ++n) {
      int row = wn * 32 + n * 16 + (lane & 15);
      const char* base = (const char*)sB[cur] + row * 128;
      bhf[n] = *(const half8*)(base + (((g2) ^ (row & 7)) << 4));
      blf[n] = *(const half8*)(base + (((g2 + 1) ^ (row & 7)) << 4));
    }
    __builtin_amdgcn_s_setprio(1);
#pragma unroll
    for (int m = 0; m < 4; ++m) {
      int row = wm * 64 + m * 16 + (lane & 15);
      const char* base = (const char*)sA[cur] + row * 128;
      half8 af = *(const half8*)(base + (((g2) ^ (row & 7)) << 4));
      half8 alf = *(const half8*)(base + (((g2 + 1) ^ (row & 7)) << 4));
#pragma unroll
      for (int n = 0; n < 2; ++n) {
        acc[m][n] = __builtin_amdgcn_mfma_f32_16x16x32_f16(af, bhf[n], acc[m][n], 0, 0, 0);
        acc[m][n] = __builtin_amdgcn_mfma_f32_16x16x32_f16(af, blf[n], acc[m][n], 0, 0, 0);
        acc[m][n] = __builtin_amdgcn_mfma_f32_16x16x32_f16(alf, bhf[n], acc[m][n], 0, 0, 0);
      }
    }
    __builtin_amdgcn_s_setprio(0);
    __builtin_amdgcn_s_barrier();
  }
  // epilogue: C row = (lane>>4)*4+j (within 16), col = lane&15
#pragma unroll
  for (int m = 0; m < 4; ++m) {
    int lrow = wm * 64 + m * 16 + ((lane >> 4) << 2);
#pragma unroll
    for (int n = 0; n < 2; ++n) {
      int gcol = nt * 128 + wn * 32 + n * 16 + (lane & 15);
      f32x4 a = acc[m][n];
#pragma unroll
      for (int j = 0; j < 4; ++j) {
        int grow = mt * 128 + lrow + j;
        float v = a[j];
        if (EPI == 0) {
          int sec = gcol >> 10, cc = gcol & 1023;
          v += (sec == 0 ? bias0[cc] : (sec == 1 ? bias1[cc] : bias2[cc]));
          int hh = cc >> 6, dd = cc & 63;
          int bb = grow >> 10, tt = grow & 1023;
          size_t dst = (((size_t)(bb * 16 + hh)) * 1024 + tt) * 64 + dd;
          _Float16 hi = (_Float16)v;
          _Float16 lo = (_Float16)(v - (float)hi);
          if (sec == 0) { q_h[dst] = hi; q_l[dst] = lo; }
          else if (sec == 1) { k_h[dst] = hi; k_l[dst] = lo; }
          else { v_h[dst] = hi; v_l[dst] = lo; }
        } else {
          v += bias0[gcol];
          outf[(size_t)grow * N + gcol] = v;
        }
      }
    }
  }
}

// ---------------- flash attention, swapped 32x32 MFMA, fp16x3 ----------------
// qblk = (blk&7) + wv*8: every block holds {x, x+8, x+16, x+24} -> equal causal work per block.
__global__ __launch_bounds__(256) void attn_kernel(
    const _Float16* __restrict__ qhp, const _Float16* __restrict__ qlp,
    const _Float16* __restrict__ khp, const _Float16* __restrict__ klp,
    const _Float16* __restrict__ vth, const _Float16* __restrict__ vtl,
    const int* __restrict__ amask,
    _Float16* __restrict__ ohp, _Float16* __restrict__ olp) {
  const int lane = threadIdx.x & 63;
  const int wv = threadIdx.x >> 6;
  const int bh = blockIdx.x >> 3;
  const int qblk = (blockIdx.x & 7) + wv * 8;      // 0..31, balanced across waves
  const int b = bh >> 4, hh = bh & 15;
  const int q0 = qblk * 32;
  const int qln = lane & 31;
  const int qq = q0 + qln;
  const int hf = lane >> 5;
  __shared__ float lmadd[1024];
  for (int i = threadIdx.x; i < 1024; i += 256) lmadd[i] = (amask[b * 1024 + i] > 0) ? 0.f : -1e9f;
  __syncthreads();

  size_t qoff = ((size_t)bh * 1024 + qq) * 64 + hf * 8;
  half8 qfh[4], qfl[4];
#pragma unroll
  for (int d = 0; d < 4; ++d) {
    qfh[d] = *(const half8*)(qhp + qoff + d * 16);
    qfl[d] = *(const half8*)(qlp + qoff + d * 16);
  }
  f32x16 o0 = zero16(), o1 = zero16();
  float mrun = -3.0e38f, lsum = 0.f;
  const float LOG2E = 1.44269504088896f;

  for (int kb = 0; kb <= qblk; ++kb) {
    size_t koff = ((size_t)bh * 1024 + kb * 32 + qln) * 64 + hf * 8;
    f32x16 s = zero16();
#pragma unroll
    for (int d = 0; d < 4; ++d) {
      half8 kfh = *(const half8*)(khp + koff + d * 16);
      half8 kfl = *(const half8*)(klp + koff + d * 16);
      s = __builtin_amdgcn_mfma_f32_32x32x16_f16(kfh, qfh[d], s, 0, 0, 0);
      s = __builtin_amdgcn_mfma_f32_32x32x16_f16(kfh, qfl[d], s, 0, 0, 0);
      s = __builtin_amdgcn_mfma_f32_32x32x16_f16(kfl, qfh[d], s, 0, 0, 0);
    }
    float sc[16];
#pragma unroll
    for (int r = 0; r < 16; ++r) {
      int krow = (r & 3) + ((r >> 2) << 3) + (hf << 2);
      int key = kb * 32 + krow;
      sc[r] = s[r] * 0.125f + lmadd[key];
    }
    if (kb == qblk) {
#pragma unroll
      for (int r = 0; r < 16; ++r) {
        int krow = (r & 3) + ((r >> 2) << 3) + (hf << 2);
        if (kb * 32 + krow > qq) sc[r] = -1e9f;
      }
    }
    float pm = sc[0];
#pragma unroll
    for (int r = 1; r < 16; ++r) pm = fmaxf(pm, sc[r]);
    pm = fmaxf(pm, __shfl_xor(pm, 32));
    float mnew = fmaxf(mrun, pm);
    float aold = exp2f((mrun - mnew) * LOG2E);
    float p[16]; float psum = 0.f;
#pragma unroll
    for (int r = 0; r < 16; ++r) { p[r] = exp2f((sc[r] - mnew) * LOG2E); psum += p[r]; }
    lsum = lsum * aold + psum;
#pragma unroll
    for (int j = 0; j < 16; ++j) { o0[j] *= aold; o1[j] *= aold; }
    mrun = mnew;
    // split P into fp16 hi/lo packed pairs
    u32 hd[8], ld[8];
#pragma unroll
    for (int i = 0; i < 8; ++i) {
      _Float16 h0 = (_Float16)p[2 * i], h1 = (_Float16)p[2 * i + 1];
      hd[i] = pkh2(h0, h1);
      ld[i] = pkh2((_Float16)(p[2 * i] - (float)h0), (_Float16)(p[2 * i + 1] - (float)h1));
    }
    auto mkfrag = [&](u32 d0, u32 d1, u32 d2, u32 d3) -> half8 {
      u32 e0 = (u32)__shfl_xor((int)d0, 32);
      u32 e1 = (u32)__shfl_xor((int)d1, 32);
      u32 e2 = (u32)__shfl_xor((int)d2, 32);
      u32 e3 = (u32)__shfl_xor((int)d3, 32);
      H8U t;
      t.u[0] = hf ? e2 : d0;
      t.u[1] = hf ? e3 : d1;
      t.u[2] = hf ? d2 : e0;
      t.u[3] = hf ? d3 : e1;
      return t.h;
    };
    half8 pbh0 = mkfrag(hd[0], hd[1], hd[2], hd[3]);
    half8 pbl0 = mkfrag(ld[0], ld[1], ld[2], ld[3]);
    half8 pbh1 = mkfrag(hd[4], hd[5], hd[6], hd[7]);
    half8 pbl1 = mkfrag(ld[4], ld[5], ld[6], ld[7]);
    // V^T fragments: rows = d (dtile 0: 0..31, dtile 1: 32..63), k = keys
    size_t vb = ((size_t)bh * 64 + qln) * 1024 + kb * 32 + hf * 8;
    half8 vh00 = *(const half8*)(vth + vb);
    half8 vh01 = *(const half8*)(vth + vb + 16);
    half8 vh10 = *(const half8*)(vth + vb + 32 * 1024);
    half8 vh11 = *(const half8*)(vth + vb + 32 * 1024 + 16);
    half8 vl00 = *(const half8*)(vtl + vb);
    half8 vl01 = *(const half8*)(vtl + vb + 16);
    half8 vl10 = *(const half8*)(vtl + vb + 32 * 1024);
    half8 vl11 = *(const half8*)(vtl + vb + 32 * 1024 + 16);
    o0 = __builtin_amdgcn_mfma_f32_32x32x16_f16(vh00, pbh0, o0, 0, 0, 0);
    o0 = __builtin_amdgcn_mfma_f32_32x32x16_f16(vh00, pbl0, o0, 0, 0, 0);
    o0 = __builtin_amdgcn_mfma_f32_32x32x16_f16(vl00, pbh0, o0, 0, 0, 0);
    o0 = __builtin_amdgcn_mfma_f32_32x32x16_f16(vh01, pbh1, o0, 0, 0, 0);
    o0 = __builtin_amdgcn_mfma_f32_32x32x16_f16(vh01, pbl1, o0, 0, 0, 0);
    o0 = __builtin_amdgcn_mfma_f32_32x32x16_f16(vl01, pbh1, o0, 0, 0, 0);
    o1 = __builtin_amdgcn_mfma_f32_32x32x16_f16(vh10, pbh0, o1, 0, 0, 0);
    o1 = __builtin_amdgcn_mfma_f32_32x32x16_f16(vh10, pbl0, o1, 0, 0, 0);
    o1 = __builtin_amdgcn_mfma_f32_32x32x16_f16(vl10, pbh0, o1, 0, 0, 0);
    o1 = __builtin_amdgcn_mfma_f32_32x32x16_f16(vh11, pbh1, o1, 0, 0, 0);
    o1 = __builtin_amdgcn_mfma_f32_32x32x16_f16(vh11, pbl1, o1, 0, 0, 0);
    o1 = __builtin_amdgcn_mfma_f32_32x32x16_f16(vl11, pbh1, o1, 0, 0, 0);
  }
  lsum += __shfl_xor(lsum, 32);
  float inv = 1.f / lsum;
  size_t obase = ((size_t)(b * 1024 + qq)) * 1024 + hh * 64;
#pragma unroll
  for (int dt = 0; dt < 2; ++dt) {
#pragma unroll
    for (int c = 0; c < 4; ++c) {
      int dloc = dt * 32 + c * 8 + hf * 4;
      float v0, v1, v2, v3;
      if (dt == 0) { v0 = o0[4 * c] * inv; v1 = o0[4 * c + 1] * inv; v2 = o0[4 * c + 2] * inv; v3 = o0[4 * c + 3] * inv; }
      else { v0 = o1[4 * c] * inv; v1 = o1[4 * c + 1] * inv; v2 = o1[4 * c + 2] * inv; v3 = o1[4 * c + 3] * inv; }
      _Float16 h0 = (_Float16)v0, h1 = (_Float16)v1, h2 = (_Float16)v2, h3 = (_Float16)v3;
      *(uint2*)(ohp + obase + dloc) = make_uint2(pkh2(h0, h1), pkh2(h2, h3));
      *(uint2*)(olp + obase + dloc) = make_uint2(
          pkh2((_Float16)(v0 - (float)h0), (_Float16)(v1 - (float)h1)),
          pkh2((_Float16)(v2 - (float)h2), (_Float16)(v3 - (float)h3)));
    }
  }
}

// ---------------- LN1: x1 = LN(x + mha), write fp32 + bf16 ----------------
__global__ __launch_bounds__(256) void ln1_kernel(
    const float* __restrict__ x, const float* __restrict__ mha,
    const float* __restrict__ gam, const float* __restrict__ bet,
    float* __restrict__ x1f, u16* __restrict__ x1b) {
  int t = blockIdx.x, tid = threadIdx.x;
  const float* xr = x + (size_t)t * 1024;
  const float* mr = mha + (size_t)t * 1024;
  float v[4], s = 0.f, ss = 0.f;
#pragma unroll
  for (int i = 0; i < 4; ++i) { int c = tid + i * 256; float a = xr[c] + mr[c]; v[i] = a; s += a; ss += a * a; }
#pragma unroll
  for (int o = 32; o; o >>= 1) { s += __shfl_xor(s, o); ss += __shfl_xor(ss, o); }
  __shared__ float rs[4], rss[4];
  int wv = tid >> 6;
  if ((tid & 63) == 0) { rs[wv] = s; rss[wv] = ss; }
  __syncthreads();
  s = rs[0] + rs[1] + rs[2] + rs[3];
  ss = rss[0] + rss[1] + rss[2] + rss[3];
  float mean = s * (1.f / 1024.f);
  float var = ss * (1.f / 1024.f) - mean * mean;
  float rstd = rsqrtf(var + 1e-5f);
#pragma unroll
  for (int i = 0; i < 4; ++i) {
    int c = tid + i * 256;
    float y = (v[i] - mean) * rstd * gam[c] + bet[c];
    x1f[(size_t)t * 1024 + c] = y;
    x1b[(size_t)t * 1024 + c] = f2bf(y);
  }
}

// ---------------- router: logits -> probs buffer + top-2 + gates (NO global atomics) ----------------
__global__ __launch_bounds__(256) void router_kernel(
    const float* __restrict__ x1f, const float* __restrict__ Wr, const float* __restrict__ br,
    int* __restrict__ eids, float* __restrict__ gatesv, float* __restrict__ probbuf) {
  int wv = threadIdx.x >> 6, lane = threadIdx.x & 63;
  int t = blockIdx.x * 4 + wv;
  const float* xr = x1f + (size_t)t * 1024;
  float acc[8];
#pragma unroll
  for (int e = 0; e < 8; ++e) acc[e] = 0.f;
  for (int c = lane; c < 1024; c += 64) {
    float xv = xr[c];
    const float* wr = Wr + c * 8;
#pragma unroll
    for (int e = 0; e < 8; ++e) acc[e] += xv * wr[e];
  }
#pragma unroll
  for (int e = 0; e < 8; ++e) {
#pragma unroll
    for (int o = 32; o; o >>= 1) acc[e] += __shfl_xor(acc[e], o);
    acc[e] += br[e];
  }
  if (lane == 0) {
    float mx = acc[0];
#pragma unroll
    for (int e = 1; e < 8; ++e) mx = fmaxf(mx, acc[e]);
    float pe[8], se = 0.f;
#pragma unroll
    for (int e = 0; e < 8; ++e) { pe[e] = expf(acc[e] - mx); se += pe[e]; }
    float inv = 1.f / se;
#pragma unroll
    for (int e = 0; e < 8; ++e) probbuf[(size_t)t * 8 + e] = pe[e] * inv;
    int i0 = 0;
#pragma unroll
    for (int e = 1; e < 8; ++e) if (acc[e] > acc[i0]) i0 = e;
    int i1 = -1;
#pragma unroll
    for (int e = 0; e < 8; ++e) if (e != i0 && (i1 < 0 || acc[e] > acc[i1])) i1 = e;
    float m2 = fmaxf(acc[i0], acc[i1]);
    float g0 = expf(acc[i0] - m2), g1 = expf(acc[i1] - m2);
    float gs = 1.f / (g0 + g1);
    eids[t * 2] = i0; eids[t * 2 + 1] = i1;
    gatesv[t * 2] = g0 * gs; gatesv[t * 2 + 1] = g1 * gs;
  }
}

// ---------------- counts + offsets from eids (single block, LDS atomics) ----------------
__global__ __launch_bounds__(256) void count_offs_kernel(
    const int* __restrict__ eids, int* __restrict__ counts, int* __restrict__ offs) {
  __shared__ int lc[8];
  if (threadIdx.x < 8) lc[threadIdx.x] = 0;
  __syncthreads();
  for (int i = threadIdx.x; i < TOK * 2; i += 256) atomicAdd(&lc[eids[i]], 1);
  __syncthreads();
  if (threadIdx.x == 0) {
    int s = 0;
#pragma unroll
    for (int e = 0; e < 8; ++e) { counts[e] = lc[e]; offs[e] = s; s += lc[e]; }
    offs[8] = s;
  }
}

// ---------------- scatter with wave-aggregated cursor atomics ----------------
__global__ __launch_bounds__(256) void scatter_kernel(
    const int* __restrict__ eids, const int* __restrict__ offs, int* __restrict__ cursor,
    int* __restrict__ tlist, int* __restrict__ invx) {
  int t = blockIdx.x * 256 + threadIdx.x;
  int lane = threadIdx.x & 63;
#pragma unroll
  for (int s = 0; s < 2; ++s) {
    int e = eids[t * 2 + s];
#pragma unroll
    for (int ex = 0; ex < 8; ++ex) {
      u64 m = __ballot(e == ex);
      if (e == ex) {
        int leader = __ffsll((long long)m) - 1;
        int rank = __popcll(m & ((1ull << lane) - 1ull));
        int base = 0;
        if (lane == leader) base = atomicAdd(&cursor[ex], __popcll(m));
        base = __shfl(base, leader);
        int idx = offs[ex] + base + rank;
        tlist[idx] = t;
        invx[t * 2 + s] = idx;
      }
    }
  }
}

// ---------------- grouped bf16 GEMM, 256x256 tile, 512 thr / 8 waves (2Mx4N), BK=32 ----------------
// 2-phase counted pipeline (issue STAGE before compute; one vmcnt(0)+barrier per K-step).
// 64 KB LDS (2 blocks/CU): line r = {A(r) 4x16B, B(r) 4x16B}, slot ((mat<<2)|gg)^(r&7)
// (R11-verified zero-conflict involution, 128 B rows). Doubles arithmetic intensity vs 128^2
// -> halves L2 operand traffic (the measured ~490 TF wall).
// EPI 2 = FF1 (gather via tlist, +b1, relu, bf16 out), EPI 3 = FF2 K-split (+b2 half0, bf16 partials)
template <int EPI>
__global__ __launch_bounds__(512, 2) void gemm_bf16_kernel(
    const u16* __restrict__ Abase, const u16* __restrict__ Bbase, const float* __restrict__ bias,
    u16* __restrict__ outb, const int* __restrict__ tlist, const int* __restrict__ offs,
    int K, int ldA, int N, int MT, int NTILES) {
  int bid = blockIdx.x;
  int e = bid / (MT * NTILES);
  int rem = bid % (MT * NTILES);
  int mt = rem / NTILES, nt = rem % NTILES;
  int mstart = offs[e], mend = offs[e + 1];
  int ne = mend - mstart;
  if (mt * 256 >= ne) return;
  const int half = blockIdx.y;
  const int kOff = half * K;
  const u16* Bt = Bbase + (size_t)e * N * ldA;
  const float* bvec = bias + (size_t)e * N;
  __shared__ __align__(16) u16 sAB[2][256 * 64];     // 256 lines x 128 B per buf (32 KB), dbuf = 64 KB
  const int tid = threadIdx.x;
  const int lane = tid & 63, wv = tid >> 6;
  const int wr = wv >> 2, wc = wv & 3;               // wave tile 128x64
  f32x4 acc[8][4];
#pragma unroll
  for (int m = 0; m < 8; ++m)
#pragma unroll
    for (int n = 0; n < 4; ++n) acc[m][n] = zero4();

  // staging: 4 slots/thread; flat -> line r = flat>>3, sg = flat&7, v = sg^(r&7):
  // mat = v>>2 (0=A,1=B), chunk = v&3
  const u16* src[4];
#pragma unroll
  for (int j = 0; j < 4; ++j) {
    int flat = j * 512 + tid;
    int r = flat >> 3, sg = flat & 7, v = sg ^ (r & 7);
    int mat = v >> 2, ch = v & 3;
    if (mat == 0) {
      int rl = mt * 256 + r;
      if (rl >= ne) rl = ne - 1;
      size_t arow = (EPI == 2) ? (size_t)tlist[mstart + rl] : (size_t)(mstart + rl);
      src[j] = Abase + arow * ldA + kOff + ch * 8;
    } else {
      src[j] = Bt + (size_t)(nt * 256 + r) * ldA + kOff + ch * 8;
    }
  }

  const int nkt = K >> 5;
  // prologue: stage K-tile 0 into buf 0, drain, barrier
#pragma unroll
  for (int j = 0; j < 4; ++j) gload16(src[j], (char*)sAB[0] + (j * 512 + tid) * 16);
  asm volatile("s_waitcnt vmcnt(0)" ::: "memory");
  __builtin_amdgcn_s_barrier();

  for (int kt = 0; kt < nkt; ++kt) {
    const int cur = kt & 1;
    if (kt + 1 < nkt) {       // issue next-tile loads BEFORE compute (they fly under MFMA)
#pragma unroll
      for (int j = 0; j < 4; ++j) gload16(src[j] + (kt + 1) * 32, (char*)sAB[cur ^ 1] + (j * 512 + tid) * 16);
    }
    const int gg = lane >> 4;                         // k-octet 0..3 (covers BK=32)
    const char* base = (const char*)sAB[cur];
    short8 bfr[4];
#pragma unroll
    for (int n = 0; n < 4; ++n) {
      int R = wc * 64 + n * 16 + (lane & 15);
      bfr[n] = *(const short8*)(base + R * 128 + (((4 | gg) ^ (R & 7)) << 4));
    }
    __builtin_amdgcn_s_setprio(1);
#pragma unroll
    for (int m = 0; m < 8; ++m) {
      int R = wr * 128 + m * 16 + (lane & 15);
      short8 afr = *(const short8*)(base + R * 128 + ((gg ^ (R & 7)) << 4));
#pragma unroll
      for (int n = 0; n < 4; ++n)
        acc[m][n] = __builtin_amdgcn_mfma_f32_16x16x32_bf16(afr, bfr[n], acc[m][n], 0, 0, 0);
    }
    __builtin_amdgcn_s_setprio(0);
    asm volatile("s_waitcnt vmcnt(0)" ::: "memory");  // next buf staged (loads flew under MFMA)
    __builtin_amdgcn_s_barrier();                      // + all waves done reading cur
  }
#pragma unroll
  for (int m = 0; m < 8; ++m) {
    int lrow = wr * 128 + m * 16 + ((lane >> 4) << 2);
#pragma unroll
    for (int n = 0; n < 4; ++n) {
      int col = nt * 256 + wc * 64 + n * 16 + (lane & 15);
      f32x4 a = acc[m][n];
#pragma unroll
      for (int j = 0; j < 4; ++j) {
        int rl = mt * 256 + lrow + j;
        if (rl < ne) {
          size_t pair = (size_t)(mstart + rl);
          float v = a[j] + ((EPI == 2 || half == 0) ? bvec[col] : 0.f);
          if (EPI == 2) { v = fmaxf(v, 0.f); outb[pair * N + col] = f2bf(v); }
          else outb[((size_t)half * 8192 + pair) * N + col] = f2bf(v);   // bf16 partials
        }
      }
    }
  }
}

// ---------------- LN2 + MoE combine (sum bf16 K-split partials) -> d_out ----------------
__global__ __launch_bounds__(256) void ln2_kernel(
    const float* __restrict__ x1f, const u16* __restrict__ oe,
    const int* __restrict__ invx, const float* __restrict__ gatesv,
    const float* __restrict__ gam, const float* __restrict__ bet, float* __restrict__ out) {
  int t = blockIdx.x, tid = threadIdx.x;
  int i0 = invx[t * 2], i1 = invx[t * 2 + 1];
  float g0 = gatesv[t * 2], g1 = gatesv[t * 2 + 1];
  const u16* r0a = oe + (size_t)i0 * 1024;
  const u16* r0b = oe + (size_t)(8192 + i0) * 1024;
  const u16* r1a = oe + (size_t)i1 * 1024;
  const u16* r1b = oe + (size_t)(8192 + i1) * 1024;
  const float* xr = x1f + (size_t)t * 1024;
  float v[4], s = 0.f, ss = 0.f;
#pragma unroll
  for (int i = 0; i < 4; ++i) {
    int c = tid + i * 256;
    float a = xr[c] + g0 * (bf2f(r0a[c]) + bf2f(r0b[c])) + g1 * (bf2f(r1a[c]) + bf2f(r1b[c]));
    v[i] = a; s += a; ss += a * a;
  }
#pragma unroll
  for (int o = 32; o; o >>= 1) { s += __shfl_xor(s, o); ss += __shfl_xor(ss, o); }
  __shared__ float rs[4], rss[4];
  int wv = tid >> 6;
  if ((tid & 63) == 0) { rs[wv] = s; rss[wv] = ss; }
  __syncthreads();
  s = rs[0] + rs[1] + rs[2] + rs[3];
  ss = rss[0] + rss[1] + rss[2] + rss[3];
  float mean = s * (1.f / 1024.f);
  float var = ss * (1.f / 1024.f) - mean * mean;
  float rstd = rsqrtf(var + 1e-5f);
#pragma unroll
  for (int i = 0; i < 4; ++i) {
    int c = tid + i * 256;
    out[(size_t)t * 1024 + c] = (v[i] - mean) * rstd * gam[c] + bet[c];
  }
}

// ---------------- lb_loss: reduce probbuf + counts (single block) ----------------
__global__ __launch_bounds__(256) void loss_kernel(
    const float* __restrict__ probbuf, const int* __restrict__ counts,
    float* __restrict__ out) {
  __shared__ float ps[256][8];
  float a[8];
#pragma unroll
  for (int e = 0; e < 8; ++e) a[e] = 0.f;
  for (int r = threadIdx.x; r < TOK; r += 256) {
#pragma unroll
    for (int e = 0; e < 8; ++e) a[e] += probbuf[(size_t)r * 8 + e];
  }
#pragma unroll
  for (int e = 0; e < 8; ++e) ps[threadIdx.x][e] = a[e];
  __syncthreads();
  if (threadIdx.x == 0) {
    float s = 0.f;
#pragma unroll
    for (int e = 0; e < 8; ++e) {
      float imp = 0.f;
      for (int i = 0; i < 256; ++i) imp += ps[i][e];
      s += (imp * (1.f / 4096.f)) * ((float)counts[e] * (1.f / 4096.f));
    }
    out[0] = 8.f * s;
  }
}

// =========================================================================
extern "C" void kernel_launch(void* const* d_in, const int* in_sizes, int n_in,
                              void* d_out, int out_size, void* d_ws, size_t ws_size,
                              hipStream_t stream) {
  const float* x = (const float*)d_in[0];
  const int* amask = (const int*)d_in[1];
  const float* Wq = (const float*)d_in[2]; const float* bq = (const float*)d_in[3];
  const float* Wk = (const float*)d_in[4]; const float* bk = (const float*)d_in[5];
  const float* Wv = (const float*)d_in[6]; const float* bv = (const float*)d_in[7];
  const float* Wo = (const float*)d_in[8]; const float* bo = (const float*)d_in[9];
  const float* g1 = (const float*)d_in[10]; const float* be1 = (const float*)d_in[11];
  const float* g2 = (const float*)d_in[12]; const float* be2 = (const float*)d_in[13];
  const float* Wr = (const float*)d_in[14]; const float* br = (const float*)d_in[15];
  const float* W1 = (const float*)d_in[16]; const float* b1 = (const float*)d_in[17];
  const float* W2 = (const float*)d_in[18]; const float* b2 = (const float*)d_in[19];
  float* out = (float*)d_out;

  char* w = (char*)d_ws;
  auto alloc = [&](size_t bytes) -> char* {
    char* p = w; w += (bytes + 255) & ~(size_t)255; return p;
  };
  _Float16* xsh = (_Float16*)alloc((size_t)TOK * CCD * 2);
  _Float16* xsl = (_Float16*)alloc((size_t)TOK * CCD * 2);
  _Float16* wqh = (_Float16*)alloc((size_t)3072 * 1024 * 2);
  _Float16* wql = (_Float16*)alloc((size_t)3072 * 1024 * 2);
  _Float16* woh = (_Float16*)alloc((size_t)1024 * 1024 * 2);
  _Float16* wol = (_Float16*)alloc((size_t)1024 * 1024 * 2);
  _Float16* qhi = (_Float16*)alloc((size_t)TOK * CCD * 2);   // oe aliases qhi..klo (32 MB)
  _Float16* qlo = (_Float16*)alloc((size_t)TOK * CCD * 2);
  _Float16* khi = (_Float16*)alloc((size_t)TOK * CCD * 2);
  _Float16* klo = (_Float16*)alloc((size_t)TOK * CCD * 2);
  _Float16* vhi = (_Float16*)alloc((size_t)TOK * CCD * 2);
  _Float16* vlo = (_Float16*)alloc((size_t)TOK * CCD * 2);
  _Float16* vthi = (_Float16*)alloc((size_t)TOK * CCD * 2);
  _Float16* vtlo = (_Float16*)alloc((size_t)TOK * CCD * 2);
  _Float16* ohi = (_Float16*)alloc((size_t)TOK * CCD * 2);
  _Float16* olo = (_Float16*)alloc((size_t)TOK * CCD * 2);
  float* mha = (float*)alloc((size_t)TOK * CCD * 4);
  float* x1f = (float*)alloc((size_t)TOK * CCD * 4);
  u16* x1b = (u16*)alloc((size_t)TOK * CCD * 2);
  u16* w1t = (u16*)alloc((size_t)8 * HIDD * CCD * 2);
  u16* w2t = (u16*)alloc((size_t)8 * CCD * HIDD * 2);
  u16* hbuf = (u16*)alloc((size_t)8192 * HIDD * 2);
  float* probbuf = (float*)alloc((size_t)TOK * 8 * 4);
  int* eids = (int*)alloc(TOK * 2 * 4);
  float* gatesv = (float*)alloc(TOK * 2 * 4);
  int* invx = (int*)alloc(TOK * 2 * 4);
  int* tlist = (int*)alloc(8192 * 4);
  char* ctrl = alloc(4096);
  int* counts = (int*)ctrl;
  int* cursor = counts + 8;
  int* offs = counts + 16;           // 9 ints
  u16* oe = (u16*)qhi;               // 2 x 8192 x 1024 bf16 partials = 32 MB; q/k dead by FF2

  hipMemsetAsync(ctrl, 0, 256, stream);

  cast_split_kernel<<<4096, 256, 0, stream>>>(x, xsh, xsl);
  trans_split_kernel<<<dim3(32, 32), 256, 0, stream>>>(Wq, wqh, wql, 1024, 1024);
  trans_split_kernel<<<dim3(32, 32), 256, 0, stream>>>(Wk, wqh + (size_t)1024 * 1024, wql + (size_t)1024 * 1024, 1024, 1024);
  trans_split_kernel<<<dim3(32, 32), 256, 0, stream>>>(Wv, wqh + (size_t)2048 * 1024, wql + (size_t)2048 * 1024, 1024, 1024);
  trans_split_kernel<<<dim3(32, 32), 256, 0, stream>>>(Wo, woh, wol, 1024, 1024);
  trans_bf16_kernel<<<dim3(16, 128, 8), 256, 0, stream>>>(W1, w1t, 1024, 4096);
  trans_bf16_kernel<<<dim3(64, 32, 8), 256, 0, stream>>>(W2, w2t, 4096, 1024);

  gemm_f16x3_kernel<0><<<dim3(32, 24), 512, 0, stream>>>(
      xsh, xsl, wqh, wql, bq, bk, bv,
      qhi, qlo, khi, klo, vhi, vlo, nullptr, 4096, 3072, 1024);
  vtrans_kernel<<<dim3(16, 2, 64), 256, 0, stream>>>(vhi, vlo, vthi, vtlo);
  attn_kernel<<<512, 256, 0, stream>>>(qhi, qlo, khi, klo, vthi, vtlo, amask, ohi, olo);
  gemm_f16x3_kernel<1><<<dim3(32, 8), 512, 0, stream>>>(
      ohi, olo, woh, wol, bo, nullptr, nullptr,
      nullptr, nullptr, nullptr, nullptr, nullptr, nullptr, mha, 4096, 1024, 1024);
  ln1_kernel<<<4096, 256, 0, stream>>>(x, mha, g1, be1, x1f, x1b);
  router_kernel<<<1024, 256, 0, stream>>>(x1f, Wr, br, eids, gatesv, probbuf);
  count_offs_kernel<<<1, 256, 0, stream>>>(eids, counts, offs);
  scatter_kernel<<<16, 256, 0, stream>>>(eids, offs, cursor, tlist, invx);
  // FF1: 256^2 tiles -> MT=16 (4096 rows/expert max), NTILES=4096/256=16
  gemm_bf16_kernel<2><<<dim3(8 * 16 * 16, 1), 512, 0, stream>>>(
      x1b, w1t, b1, hbuf, tlist, offs, 1024, 1024, 4096, 16, 16);
  // FF2: K split in 2 halves of 2048; NTILES=1024/256=4
  gemm_bf16_kernel<3><<<dim3(8 * 16 * 4, 2), 512, 0, stream>>>(
      hbuf, w2t, b2, oe, nullptr, offs, 2048, 4096, 1024, 16, 4);
  ln2_kernel<<<4096, 256, 0, stream>>>(x1f, oe, invx, gatesv, g2, be2, out);
  loss_kernel<<<1, 256, 0, stream>>>(probbuf, counts, out + (size_t)TOK * CCD);
}

// Round 14
// 681.566 us; speedup vs baseline: 1.1186x; 1.1186x over previous
//
#include <hip/hip_runtime.h>
#include <hip/hip_bf16.h>

typedef unsigned short u16;
typedef unsigned int u32;
typedef unsigned long long u64;
typedef __attribute__((ext_vector_type(8))) _Float16 half8;
typedef __attribute__((ext_vector_type(8))) short short8;
typedef __attribute__((ext_vector_type(4))) float f32x4;
typedef __attribute__((ext_vector_type(16))) float f32x16;
typedef __attribute__((ext_vector_type(4))) int int4v;

#define DEVI __device__ __forceinline__

static constexpr int TOK = 4096;     // B*T
static constexpr int CCD = 1024;     // C
static constexpr int HIDD = 4096;    // 4C
static constexpr int MAXMT = 32;     // worst-case M-tiles per expert (4096/128)

DEVI u16 f2bf(float f) {             // RNE float->bf16 (finite inputs)
  u32 u = __builtin_bit_cast(u32, f);
  u32 r = (u + 0x7fffu + ((u >> 16) & 1u)) >> 16;
  return (u16)r;
}
DEVI float bf2f(u16 v) { u32 u = ((u32)v) << 16; return __builtin_bit_cast(float, u); }
DEVI u32 pkh2(_Float16 a, _Float16 b) {
  u16 ua = __builtin_bit_cast(u16, a), ub = __builtin_bit_cast(u16, b);
  return (u32)ua | ((u32)ub << 16);
}
union H8U { u32 u[4]; half8 h; };
DEVI f32x16 zero16() { f32x16 z;
#pragma unroll
  for (int i = 0; i < 16; ++i) z[i] = 0.f;
  return z; }
DEVI f32x4 zero4() { f32x4 z;
#pragma unroll
  for (int i = 0; i < 4; ++i) z[i] = 0.f;
  return z; }

// async global->LDS, 16B per lane. LDS dest = wave-uniform base + lane*16 (linear).
DEVI void gload16(const void* g, void* l) {
  __builtin_amdgcn_global_load_lds(
      (const __attribute__((address_space(1))) void*)g,
      (__attribute__((address_space(3))) void*)l, 16, 0, 0);
}

// ---------------- cast x -> fp16 hi/lo ----------------
__global__ __launch_bounds__(256) void cast_split_kernel(
    const float* __restrict__ x, _Float16* __restrict__ xh, _Float16* __restrict__ xl) {
  int i = blockIdx.x * 256 + threadIdx.x;      // i indexes float4
  float4 v = ((const float4*)x)[i];
  _Float16 h0 = (_Float16)v.x, h1 = (_Float16)v.y, h2 = (_Float16)v.z, h3 = (_Float16)v.w;
  _Float16 l0 = (_Float16)(v.x - (float)h0), l1 = (_Float16)(v.y - (float)h1);
  _Float16 l2 = (_Float16)(v.z - (float)h2), l3 = (_Float16)(v.w - (float)h3);
  ((uint2*)xh)[i] = make_uint2(pkh2(h0, h1), pkh2(h2, h3));
  ((uint2*)xl)[i] = make_uint2(pkh2(l0, l1), pkh2(l2, l3));
}

// ---------------- transpose fp32 [K][N] -> fp16 split [N][K] ----------------
__global__ __launch_bounds__(256) void trans_split_kernel(
    const float* __restrict__ in, _Float16* __restrict__ oh, _Float16* __restrict__ ol,
    int K, int N) {
  __shared__ float tile[32][33];
  int k0 = blockIdx.x * 32, n0 = blockIdx.y * 32;
  int tx = threadIdx.x & 31, ty = threadIdx.x >> 5;   // ty 0..7
#pragma unroll
  for (int i = 0; i < 4; ++i) { int r = ty + i * 8; tile[r][tx] = in[(size_t)(k0 + r) * N + n0 + tx]; }
  __syncthreads();
#pragma unroll
  for (int i = 0; i < 4; ++i) {
    int r = ty + i * 8;
    float v = tile[tx][r];                    // = in[k0+tx][n0+r]
    _Float16 h = (_Float16)v;
    oh[(size_t)(n0 + r) * K + k0 + tx] = h;
    ol[(size_t)(n0 + r) * K + k0 + tx] = (_Float16)(v - (float)h);
  }
}

// ---------------- transpose fp32 [K][N] -> bf16 [N][K], 64Kx32N tiles, 16B stores ----------------
__global__ __launch_bounds__(256) void trans_bf16_kernel(
    const float* __restrict__ in, u16* __restrict__ ob, int K, int N) {
  __shared__ float tile[64][33];
  in += (size_t)blockIdx.z * K * N;
  ob += (size_t)blockIdx.z * K * N;
  int k0 = blockIdx.x * 64, n0 = blockIdx.y * 32;
  int tx = threadIdx.x & 31, ty = threadIdx.x >> 5;   // ty 0..7
#pragma unroll
  for (int i = 0; i < 8; ++i) {
    int k = ty + i * 8;
    tile[k][tx] = in[(size_t)(k0 + k) * N + n0 + tx];
  }
  __syncthreads();
  int n = threadIdx.x >> 3, kc = (threadIdx.x & 7) * 8;
  short8 sv;
#pragma unroll
  for (int j = 0; j < 8; ++j) sv[j] = (short)f2bf(tile[kc + j][n]);
  *(short8*)(ob + (size_t)(n0 + n) * K + k0 + kc) = sv;
}

// ---------------- transpose V fp16 [bh][1024][64] -> [bh][64][1024], 16B stores ----------------
__global__ __launch_bounds__(256) void vtrans_kernel(
    const _Float16* __restrict__ vh, const _Float16* __restrict__ vl,
    _Float16* __restrict__ vth, _Float16* __restrict__ vtl) {
  __shared__ u32 t0[64][17], t1[64][17];
  size_t base = (size_t)blockIdx.z * 65536;
  int r0 = blockIdx.x * 64;   // t
  int c0 = blockIdx.y * 32;   // d
  int tx = threadIdx.x & 15, ty = threadIdx.x >> 4;   // ty 0..15
#pragma unroll
  for (int i = 0; i < 4; ++i) {
    int t = ty + i * 16;
    t0[t][tx] = *(const u32*)(vh + base + (size_t)(r0 + t) * 64 + c0 + tx * 2);
    t1[t][tx] = *(const u32*)(vl + base + (size_t)(r0 + t) * 64 + c0 + tx * 2);
  }
  __syncthreads();
  int d = threadIdx.x >> 3, tc = (threadIdx.x & 7) * 8;
  short8 sa, sb;
#pragma unroll
  for (int j = 0; j < 8; ++j) {
    u32 w0 = t0[tc + j][d >> 1], w1 = t1[tc + j][d >> 1];
    sa[j] = (short)((d & 1) ? (w0 >> 16) : (w0 & 0xffffu));
    sb[j] = (short)((d & 1) ? (w1 >> 16) : (w1 & 0xffffu));
  }
  size_t dst = base + (size_t)(c0 + d) * 1024 + r0 + tc;
  *(short8*)((u16*)vth + dst) = sa;
  *(short8*)((u16*)vtl + dst) = sb;
}

// ---------------- fp16x3 GEMM, 512 threads (8 waves, 2x4), 128x128 tile, BK=32 ----------------
// dbuf gload_lds (counted vmcnt(4)), pre-swizzled source -> conflict-free XOR reads.
// EPI 0: QKV scatter epilogue; EPI 1: fp32 out + bias0
template <int EPI>
__global__ __launch_bounds__(512, 4) void gemm_f16x3_kernel(
    const _Float16* __restrict__ Ah, const _Float16* __restrict__ Al,
    const _Float16* __restrict__ Bh, const _Float16* __restrict__ Bl,
    const float* __restrict__ bias0, const float* __restrict__ bias1, const float* __restrict__ bias2,
    _Float16* __restrict__ q_h, _Float16* __restrict__ q_l,
    _Float16* __restrict__ k_h, _Float16* __restrict__ k_l,
    _Float16* __restrict__ v_h, _Float16* __restrict__ v_l,
    float* __restrict__ outf, int M, int N, int K) {
  __shared__ __align__(16) _Float16 sA[2][128 * 64];
  __shared__ __align__(16) _Float16 sB[2][128 * 64];
  const int tid = threadIdx.x;
  const int mt = blockIdx.x, nt = blockIdx.y;
  const int lane = tid & 63, wv = tid >> 6;
  const int wm = wv >> 2, wn = wv & 3;         // wave tile 64x32
  f32x4 acc[4][2];
#pragma unroll
  for (int m = 0; m < 4; ++m)
#pragma unroll
    for (int n = 0; n < 2; ++n) acc[m][n] = zero4();

  // slot flat -> (row, sigma); sigma holds data chunk s = sigma ^ (row&7): g=s>>1, hl=s&1
  const _Float16* aS[2]; const _Float16* bS[2];
#pragma unroll
  for (int j = 0; j < 2; ++j) {
    int flat = j * 512 + tid;
    int row = flat >> 3, sg = flat & 7, s = sg ^ (row & 7), g = s >> 1, hl = s & 1;
    aS[j] = (hl ? Al : Ah) + (size_t)(mt * 128 + row) * K + g * 8;
    bS[j] = (hl ? Bl : Bh) + (size_t)(nt * 128 + row) * K + g * 8;
  }

  const int nkt = K >> 5;
#pragma unroll
  for (int j = 0; j < 2; ++j) gload16(aS[j], (char*)sA[0] + (j * 512 + tid) * 16);
#pragma unroll
  for (int j = 0; j < 2; ++j) gload16(bS[j], (char*)sB[0] + (j * 512 + tid) * 16);

  for (int kt = 0; kt < nkt; ++kt) {
    const int cur = kt & 1;
    if (kt + 1 < nkt) {
#pragma unroll
      for (int j = 0; j < 2; ++j) gload16(aS[j] + (kt + 1) * 32, (char*)sA[cur ^ 1] + (j * 512 + tid) * 16);
#pragma unroll
      for (int j = 0; j < 2; ++j) gload16(bS[j] + (kt + 1) * 32, (char*)sB[cur ^ 1] + (j * 512 + tid) * 16);
      asm volatile("s_waitcnt vmcnt(4)" ::: "memory");
    } else {
      asm volatile("s_waitcnt vmcnt(0)" ::: "memory");
    }
    __builtin_amdgcn_s_barrier();
    const int g2 = (lane >> 4) << 1;
    half8 bhf[2], blf[2];
#pragma unroll
    for (int n = 0; n < 2; ++n) {
      int row = wn * 32 + n * 16 + (lane & 15);
      const char* base = (const char*)sB[cur] + row * 128;
      bhf[n] = *(const half8*)(base + (((g2) ^ (row & 7)) << 4));
      blf[n] = *(const half8*)(base + (((g2 + 1) ^ (row & 7)) << 4));
    }
    __builtin_amdgcn_s_setprio(1);
#pragma unroll
    for (int m = 0; m < 4; ++m) {
      int row = wm * 64 + m * 16 + (lane & 15);
      const char* base = (const char*)sA[cur] + row * 128;
      half8 af = *(const half8*)(base + (((g2) ^ (row & 7)) << 4));
      half8 alf = *(const half8*)(base + (((g2 + 1) ^ (row & 7)) << 4));
#pragma unroll
      for (int n = 0; n < 2; ++n) {
        acc[m][n] = __builtin_amdgcn_mfma_f32_16x16x32_f16(af, bhf[n], acc[m][n], 0, 0, 0);
        acc[m][n] = __builtin_amdgcn_mfma_f32_16x16x32_f16(af, blf[n], acc[m][n], 0, 0, 0);
        acc[m][n] = __builtin_amdgcn_mfma_f32_16x16x32_f16(alf, bhf[n], acc[m][n], 0, 0, 0);
      }
    }
    __builtin_amdgcn_s_setprio(0);
    __builtin_amdgcn_s_barrier();
  }
  // epilogue: C row = (lane>>4)*4+j (within 16), col = lane&15
#pragma unroll
  for (int m = 0; m < 4; ++m) {
    int lrow = wm * 64 + m * 16 + ((lane >> 4) << 2);
#pragma unroll
    for (int n = 0; n < 2; ++n) {
      int gcol = nt * 128 + wn * 32 + n * 16 + (lane & 15);
      f32x4 a = acc[m][n];
#pragma unroll
      for (int j = 0; j < 4; ++j) {
        int grow = mt * 128 + lrow + j;
        float v = a[j];
        if (EPI == 0) {
          int sec = gcol >> 10, cc = gcol & 1023;
          v += (sec == 0 ? bias0[cc] : (sec == 1 ? bias1[cc] : bias2[cc]));
          int hh = cc >> 6, dd = cc & 63;
          int bb = grow >> 10, tt = grow & 1023;
          size_t dst = (((size_t)(bb * 16 + hh)) * 1024 + tt) * 64 + dd;
          _Float16 hi = (_Float16)v;
          _Float16 lo = (_Float16)(v - (float)hi);
          if (sec == 0) { q_h[dst] = hi; q_l[dst] = lo; }
          else if (sec == 1) { k_h[dst] = hi; k_l[dst] = lo; }
          else { v_h[dst] = hi; v_l[dst] = lo; }
        } else {
          v += bias0[gcol];
          outf[(size_t)grow * N + gcol] = v;
        }
      }
    }
  }
}

// ---------------- flash attention, swapped 32x32 MFMA, fp16x3 ----------------
// qblk = (blk&7) + wv*8: every block holds {x, x+8, x+16, x+24} -> equal causal work per block.
__global__ __launch_bounds__(256) void attn_kernel(
    const _Float16* __restrict__ qhp, const _Float16* __restrict__ qlp,
    const _Float16* __restrict__ khp, const _Float16* __restrict__ klp,
    const _Float16* __restrict__ vth, const _Float16* __restrict__ vtl,
    const int* __restrict__ amask,
    _Float16* __restrict__ ohp, _Float16* __restrict__ olp) {
  const int lane = threadIdx.x & 63;
  const int wv = threadIdx.x >> 6;
  const int bh = blockIdx.x >> 3;
  const int qblk = (blockIdx.x & 7) + wv * 8;      // 0..31, balanced across waves
  const int b = bh >> 4, hh = bh & 15;
  const int q0 = qblk * 32;
  const int qln = lane & 31;
  const int qq = q0 + qln;
  const int hf = lane >> 5;
  __shared__ float lmadd[1024];
  for (int i = threadIdx.x; i < 1024; i += 256) lmadd[i] = (amask[b * 1024 + i] > 0) ? 0.f : -1e9f;
  __syncthreads();

  size_t qoff = ((size_t)bh * 1024 + qq) * 64 + hf * 8;
  half8 qfh[4], qfl[4];
#pragma unroll
  for (int d = 0; d < 4; ++d) {
    qfh[d] = *(const half8*)(qhp + qoff + d * 16);
    qfl[d] = *(const half8*)(qlp + qoff + d * 16);
  }
  f32x16 o0 = zero16(), o1 = zero16();
  float mrun = -3.0e38f, lsum = 0.f;
  const float LOG2E = 1.44269504088896f;

  for (int kb = 0; kb <= qblk; ++kb) {
    size_t koff = ((size_t)bh * 1024 + kb * 32 + qln) * 64 + hf * 8;
    f32x16 s = zero16();
#pragma unroll
    for (int d = 0; d < 4; ++d) {
      half8 kfh = *(const half8*)(khp + koff + d * 16);
      half8 kfl = *(const half8*)(klp + koff + d * 16);
      s = __builtin_amdgcn_mfma_f32_32x32x16_f16(kfh, qfh[d], s, 0, 0, 0);
      s = __builtin_amdgcn_mfma_f32_32x32x16_f16(kfh, qfl[d], s, 0, 0, 0);
      s = __builtin_amdgcn_mfma_f32_32x32x16_f16(kfl, qfh[d], s, 0, 0, 0);
    }
    float sc[16];
#pragma unroll
    for (int r = 0; r < 16; ++r) {
      int krow = (r & 3) + ((r >> 2) << 3) + (hf << 2);
      int key = kb * 32 + krow;
      sc[r] = s[r] * 0.125f + lmadd[key];
    }
    if (kb == qblk) {
#pragma unroll
      for (int r = 0; r < 16; ++r) {
        int krow = (r & 3) + ((r >> 2) << 3) + (hf << 2);
        if (kb * 32 + krow > qq) sc[r] = -1e9f;
      }
    }
    float pm = sc[0];
#pragma unroll
    for (int r = 1; r < 16; ++r) pm = fmaxf(pm, sc[r]);
    pm = fmaxf(pm, __shfl_xor(pm, 32));
    float mnew = fmaxf(mrun, pm);
    float aold = exp2f((mrun - mnew) * LOG2E);
    float p[16]; float psum = 0.f;
#pragma unroll
    for (int r = 0; r < 16; ++r) { p[r] = exp2f((sc[r] - mnew) * LOG2E); psum += p[r]; }
    lsum = lsum * aold + psum;
#pragma unroll
    for (int j = 0; j < 16; ++j) { o0[j] *= aold; o1[j] *= aold; }
    mrun = mnew;
    // split P into fp16 hi/lo packed pairs
    u32 hd[8], ld[8];
#pragma unroll
    for (int i = 0; i < 8; ++i) {
      _Float16 h0 = (_Float16)p[2 * i], h1 = (_Float16)p[2 * i + 1];
      hd[i] = pkh2(h0, h1);
      ld[i] = pkh2((_Float16)(p[2 * i] - (float)h0), (_Float16)(p[2 * i + 1] - (float)h1));
    }
    auto mkfrag = [&](u32 d0, u32 d1, u32 d2, u32 d3) -> half8 {
      u32 e0 = (u32)__shfl_xor((int)d0, 32);
      u32 e1 = (u32)__shfl_xor((int)d1, 32);
      u32 e2 = (u32)__shfl_xor((int)d2, 32);
      u32 e3 = (u32)__shfl_xor((int)d3, 32);
      H8U t;
      t.u[0] = hf ? e2 : d0;
      t.u[1] = hf ? e3 : d1;
      t.u[2] = hf ? d2 : e0;
      t.u[3] = hf ? d3 : e1;
      return t.h;
    };
    half8 pbh0 = mkfrag(hd[0], hd[1], hd[2], hd[3]);
    half8 pbl0 = mkfrag(ld[0], ld[1], ld[2], ld[3]);
    half8 pbh1 = mkfrag(hd[4], hd[5], hd[6], hd[7]);
    half8 pbl1 = mkfrag(ld[4], ld[5], ld[6], ld[7]);
    // V^T fragments: rows = d (dtile 0: 0..31, dtile 1: 32..63), k = keys
    size_t vb = ((size_t)bh * 64 + qln) * 1024 + kb * 32 + hf * 8;
    half8 vh00 = *(const half8*)(vth + vb);
    half8 vh01 = *(const half8*)(vth + vb + 16);
    half8 vh10 = *(const half8*)(vth + vb + 32 * 1024);
    half8 vh11 = *(const half8*)(vth + vb + 32 * 1024 + 16);
    half8 vl00 = *(const half8*)(vtl + vb);
    half8 vl01 = *(const half8*)(vtl + vb + 16);
    half8 vl10 = *(const half8*)(vtl + vb + 32 * 1024);
    half8 vl11 = *(const half8*)(vtl + vb + 32 * 1024 + 16);
    o0 = __builtin_amdgcn_mfma_f32_32x32x16_f16(vh00, pbh0, o0, 0, 0, 0);
    o0 = __builtin_amdgcn_mfma_f32_32x32x16_f16(vh00, pbl0, o0, 0, 0, 0);
    o0 = __builtin_amdgcn_mfma_f32_32x32x16_f16(vl00, pbh0, o0, 0, 0, 0);
    o0 = __builtin_amdgcn_mfma_f32_32x32x16_f16(vh01, pbh1, o0, 0, 0, 0);
    o0 = __builtin_amdgcn_mfma_f32_32x32x16_f16(vh01, pbl1, o0, 0, 0, 0);
    o0 = __builtin_amdgcn_mfma_f32_32x32x16_f16(vl01, pbh1, o0, 0, 0, 0);
    o1 = __builtin_amdgcn_mfma_f32_32x32x16_f16(vh10, pbh0, o1, 0, 0, 0);
    o1 = __builtin_amdgcn_mfma_f32_32x32x16_f16(vh10, pbl0, o1, 0, 0, 0);
    o1 = __builtin_amdgcn_mfma_f32_32x32x16_f16(vl10, pbh0, o1, 0, 0, 0);
    o1 = __builtin_amdgcn_mfma_f32_32x32x16_f16(vh11, pbh1, o1, 0, 0, 0);
    o1 = __builtin_amdgcn_mfma_f32_32x32x16_f16(vh11, pbl1, o1, 0, 0, 0);
    o1 = __builtin_amdgcn_mfma_f32_32x32x16_f16(vl11, pbh1, o1, 0, 0, 0);
  }
  lsum += __shfl_xor(lsum, 32);
  float inv = 1.f / lsum;
  size_t obase = ((size_t)(b * 1024 + qq)) * 1024 + hh * 64;
#pragma unroll
  for (int dt = 0; dt < 2; ++dt) {
#pragma unroll
    for (int c = 0; c < 4; ++c) {
      int dloc = dt * 32 + c * 8 + hf * 4;
      float v0, v1, v2, v3;
      if (dt == 0) { v0 = o0[4 * c] * inv; v1 = o0[4 * c + 1] * inv; v2 = o0[4 * c + 2] * inv; v3 = o0[4 * c + 3] * inv; }
      else { v0 = o1[4 * c] * inv; v1 = o1[4 * c + 1] * inv; v2 = o1[4 * c + 2] * inv; v3 = o1[4 * c + 3] * inv; }
      _Float16 h0 = (_Float16)v0, h1 = (_Float16)v1, h2 = (_Float16)v2, h3 = (_Float16)v3;
      *(uint2*)(ohp + obase + dloc) = make_uint2(pkh2(h0, h1), pkh2(h2, h3));
      *(uint2*)(olp + obase + dloc) = make_uint2(
          pkh2((_Float16)(v0 - (float)h0), (_Float16)(v1 - (float)h1)),
          pkh2((_Float16)(v2 - (float)h2), (_Float16)(v3 - (float)h3)));
    }
  }
}

// ---------------- LN1: x1 = LN(x + mha), write fp32 + bf16 ----------------
__global__ __launch_bounds__(256) void ln1_kernel(
    const float* __restrict__ x, const float* __restrict__ mha,
    const float* __restrict__ gam, const float* __restrict__ bet,
    float* __restrict__ x1f, u16* __restrict__ x1b) {
  int t = blockIdx.x, tid = threadIdx.x;
  const float* xr = x + (size_t)t * 1024;
  const float* mr = mha + (size_t)t * 1024;
  float v[4], s = 0.f, ss = 0.f;
#pragma unroll
  for (int i = 0; i < 4; ++i) { int c = tid + i * 256; float a = xr[c] + mr[c]; v[i] = a; s += a; ss += a * a; }
#pragma unroll
  for (int o = 32; o; o >>= 1) { s += __shfl_xor(s, o); ss += __shfl_xor(ss, o); }
  __shared__ float rs[4], rss[4];
  int wv = tid >> 6;
  if ((tid & 63) == 0) { rs[wv] = s; rss[wv] = ss; }
  __syncthreads();
  s = rs[0] + rs[1] + rs[2] + rs[3];
  ss = rss[0] + rss[1] + rss[2] + rss[3];
  float mean = s * (1.f / 1024.f);
  float var = ss * (1.f / 1024.f) - mean * mean;
  float rstd = rsqrtf(var + 1e-5f);
#pragma unroll
  for (int i = 0; i < 4; ++i) {
    int c = tid + i * 256;
    float y = (v[i] - mean) * rstd * gam[c] + bet[c];
    x1f[(size_t)t * 1024 + c] = y;
    x1b[(size_t)t * 1024 + c] = f2bf(y);
  }
}

// ---------------- router: logits -> probs buffer + top-2 + gates (NO global atomics) ----------------
__global__ __launch_bounds__(256) void router_kernel(
    const float* __restrict__ x1f, const float* __restrict__ Wr, const float* __restrict__ br,
    int* __restrict__ eids, float* __restrict__ gatesv, float* __restrict__ probbuf) {
  int wv = threadIdx.x >> 6, lane = threadIdx.x & 63;
  int t = blockIdx.x * 4 + wv;
  const float* xr = x1f + (size_t)t * 1024;
  float acc[8];
#pragma unroll
  for (int e = 0; e < 8; ++e) acc[e] = 0.f;
  for (int c = lane; c < 1024; c += 64) {
    float xv = xr[c];
    const float* wr = Wr + c * 8;
#pragma unroll
    for (int e = 0; e < 8; ++e) acc[e] += xv * wr[e];
  }
#pragma unroll
  for (int e = 0; e < 8; ++e) {
#pragma unroll
    for (int o = 32; o; o >>= 1) acc[e] += __shfl_xor(acc[e], o);
    acc[e] += br[e];
  }
  if (lane == 0) {
    float mx = acc[0];
#pragma unroll
    for (int e = 1; e < 8; ++e) mx = fmaxf(mx, acc[e]);
    float pe[8], se = 0.f;
#pragma unroll
    for (int e = 0; e < 8; ++e) { pe[e] = expf(acc[e] - mx); se += pe[e]; }
    float inv = 1.f / se;
#pragma unroll
    for (int e = 0; e < 8; ++e) probbuf[(size_t)t * 8 + e] = pe[e] * inv;
    int i0 = 0;
#pragma unroll
    for (int e = 1; e < 8; ++e) if (acc[e] > acc[i0]) i0 = e;
    int i1 = -1;
#pragma unroll
    for (int e = 0; e < 8; ++e) if (e != i0 && (i1 < 0 || acc[e] > acc[i1])) i1 = e;
    float m2 = fmaxf(acc[i0], acc[i1]);
    float g0 = expf(acc[i0] - m2), g1 = expf(acc[i1] - m2);
    float gs = 1.f / (g0 + g1);
    eids[t * 2] = i0; eids[t * 2 + 1] = i1;
    gatesv[t * 2] = g0 * gs; gatesv[t * 2 + 1] = g1 * gs;
  }
}

// ---------------- counts + offsets from eids (single block, LDS atomics) ----------------
__global__ __launch_bounds__(256) void count_offs_kernel(
    const int* __restrict__ eids, int* __restrict__ counts, int* __restrict__ offs) {
  __shared__ int lc[8];
  if (threadIdx.x < 8) lc[threadIdx.x] = 0;
  __syncthreads();
  for (int i = threadIdx.x; i < TOK * 2; i += 256) atomicAdd(&lc[eids[i]], 1);
  __syncthreads();
  if (threadIdx.x == 0) {
    int s = 0;
#pragma unroll
    for (int e = 0; e < 8; ++e) { counts[e] = lc[e]; offs[e] = s; s += lc[e]; }
    offs[8] = s;
  }
}

// ---------------- scatter with wave-aggregated cursor atomics ----------------
__global__ __launch_bounds__(256) void scatter_kernel(
    const int* __restrict__ eids, const int* __restrict__ offs, int* __restrict__ cursor,
    int* __restrict__ tlist, int* __restrict__ invx) {
  int t = blockIdx.x * 256 + threadIdx.x;
  int lane = threadIdx.x & 63;
#pragma unroll
  for (int s = 0; s < 2; ++s) {
    int e = eids[t * 2 + s];
#pragma unroll
    for (int ex = 0; ex < 8; ++ex) {
      u64 m = __ballot(e == ex);
      if (e == ex) {
        int leader = __ffsll((long long)m) - 1;
        int rank = __popcll(m & ((1ull << lane) - 1ull));
        int base = 0;
        if (lane == leader) base = atomicAdd(&cursor[ex], __popcll(m));
        base = __shfl(base, leader);
        int idx = offs[ex] + base + rank;
        tlist[idx] = t;
        invx[t * 2 + s] = idx;
      }
    }
  }
}

// ---------------- grouped bf16 GEMM, 512 threads, 128x128, BK=32, 3-deep pipeline ----------------
// 3 LDS slots (48 KB -> 3 blocks/CU), prefetch distance 2, counted vmcnt(4).
// Source pre-swizzled with chunk g = sg ^ (row&3); reads XOR the same way.
// EPI 2 = FF1 (gather via tlist, +b1, relu, bf16 out), EPI 3 = FF2 K-split (+b2 half0, bf16 partials)
template <int EPI>
__global__ __launch_bounds__(512, 4) void gemm_bf16_kernel(
    const u16* __restrict__ Abase, const u16* __restrict__ Bbase, const float* __restrict__ bias,
    u16* __restrict__ outb, float* __restrict__ outf,
    const int* __restrict__ tlist, const int* __restrict__ offs,
    int K, int ldA, int N, int NTILES) {
  int bid = blockIdx.x;
  int e = bid / (MAXMT * NTILES);
  int rem = bid % (MAXMT * NTILES);
  int mt = rem / NTILES, nt = rem % NTILES;          // nt fastest
  int mstart = offs[e], mend = offs[e + 1];
  int ne = mend - mstart;
  if (mt * 128 >= ne) return;
  const int half = blockIdx.y;
  const int kOff = half * K;
  const u16* Bt = Bbase + (size_t)e * N * ldA;
  const float* bvec = bias + (size_t)e * N;
  __shared__ __align__(16) u16 sA[3][128 * 32];
  __shared__ __align__(16) u16 sB[3][128 * 32];
  const int tid = threadIdx.x;
  const int lane = tid & 63, wv = tid >> 6;
  const int wm = wv >> 2, wn = wv & 3;               // wave tile 64x32
  f32x4 acc[4][2];
#pragma unroll
  for (int m = 0; m < 4; ++m)
#pragma unroll
    for (int n = 0; n < 2; ++n) acc[m][n] = zero4();

  // slot tid -> (row = tid>>2, sg = tid&3); source chunk g = sg ^ (row&3)
  const int row = tid >> 2, sg = tid & 3, g = sg ^ (row & 3);
  int rl = mt * 128 + row;
  if (rl >= ne) rl = ne - 1;
  size_t arow = (EPI == 2) ? (size_t)tlist[mstart + rl] : (size_t)(mstart + rl);
  const u16* aS = Abase + arow * ldA + kOff + g * 8;
  const u16* bS = Bt + (size_t)(nt * 128 + row) * ldA + kOff + g * 8;

  const int nkt = K >> 5;
  // prologue: stage K-tiles 0 and 1 into slots 0, 1
  gload16(aS, (char*)sA[0] + tid * 16);
  gload16(bS, (char*)sB[0] + tid * 16);
  gload16(aS + 32, (char*)sA[1] + tid * 16);
  gload16(bS + 32, (char*)sB[1] + tid * 16);

  int slot = 0;
  for (int kt = 0; kt < nkt; ++kt) {
    if (kt + 2 < nkt) {
      int ps = slot + 2; if (ps >= 3) ps -= 3;
      gload16(aS + (kt + 2) * 32, (char*)sA[ps] + tid * 16);
      gload16(bS + (kt + 2) * 32, (char*)sB[ps] + tid * 16);
    }
    int remt = nkt - 1 - kt;
    if (remt >= 2) asm volatile("s_waitcnt vmcnt(4)" ::: "memory");
    else if (remt == 1) asm volatile("s_waitcnt vmcnt(2)" ::: "memory");
    else asm volatile("s_waitcnt vmcnt(0)" ::: "memory");
    __builtin_amdgcn_s_barrier();
    const int gg = lane >> 4;                         // 0..3 chunk per K-offset
    short8 bfr[2];
#pragma unroll
    for (int n = 0; n < 2; ++n) {
      int r2 = wn * 32 + n * 16 + (lane & 15);
      bfr[n] = *(const short8*)((const char*)sB[slot] + r2 * 64 + ((gg ^ (r2 & 3)) << 4));
    }
    __builtin_amdgcn_s_setprio(1);
#pragma unroll
    for (int m = 0; m < 4; ++m) {
      int ra = wm * 64 + m * 16 + (lane & 15);
      short8 afr = *(const short8*)((const char*)sA[slot] + ra * 64 + ((gg ^ (ra & 3)) << 4));
#pragma unroll
      for (int n = 0; n < 2; ++n)
        acc[m][n] = __builtin_amdgcn_mfma_f32_16x16x32_bf16(afr, bfr[n], acc[m][n], 0, 0, 0);
    }
    __builtin_amdgcn_s_setprio(0);
    __builtin_amdgcn_s_barrier();
    ++slot; if (slot == 3) slot = 0;
  }
#pragma unroll
  for (int m = 0; m < 4; ++m) {
    int lrow = wm * 64 + m * 16 + ((lane >> 4) << 2);
#pragma unroll
    for (int n = 0; n < 2; ++n) {
      int col = nt * 128 + wn * 32 + n * 16 + (lane & 15);
      f32x4 a = acc[m][n];
#pragma unroll
      for (int j = 0; j < 4; ++j) {
        int rl2 = mt * 128 + lrow + j;
        if (rl2 < ne) {
          size_t pair = (size_t)(mstart + rl2);
          float v = a[j] + ((EPI == 2 || half == 0) ? bvec[col] : 0.f);
          if (EPI == 2) { v = fmaxf(v, 0.f); outb[pair * N + col] = f2bf(v); }
          else outb[((size_t)half * 8192 + pair) * N + col] = f2bf(v);   // bf16 partials
        }
      }
    }
  }
}

// ---------------- LN2 + MoE combine (sum bf16 K-split partials) -> d_out ----------------
__global__ __launch_bounds__(256) void ln2_kernel(
    const float* __restrict__ x1f, const u16* __restrict__ oe,
    const int* __restrict__ invx, const float* __restrict__ gatesv,
    const float* __restrict__ gam, const float* __restrict__ bet, float* __restrict__ out) {
  int t = blockIdx.x, tid = threadIdx.x;
  int i0 = invx[t * 2], i1 = invx[t * 2 + 1];
  float g0 = gatesv[t * 2], g1 = gatesv[t * 2 + 1];
  const u16* r0a = oe + (size_t)i0 * 1024;
  const u16* r0b = oe + (size_t)(8192 + i0) * 1024;
  const u16* r1a = oe + (size_t)i1 * 1024;
  const u16* r1b = oe + (size_t)(8192 + i1) * 1024;
  const float* xr = x1f + (size_t)t * 1024;
  float v[4], s = 0.f, ss = 0.f;
#pragma unroll
  for (int i = 0; i < 4; ++i) {
    int c = tid + i * 256;
    float a = xr[c] + g0 * (bf2f(r0a[c]) + bf2f(r0b[c])) + g1 * (bf2f(r1a[c]) + bf2f(r1b[c]));
    v[i] = a; s += a; ss += a * a;
  }
#pragma unroll
  for (int o = 32; o; o >>= 1) { s += __shfl_xor(s, o); ss += __shfl_xor(ss, o); }
  __shared__ float rs[4], rss[4];
  int wv = tid >> 6;
  if ((tid & 63) == 0) { rs[wv] = s; rss[wv] = ss; }
  __syncthreads();
  s = rs[0] + rs[1] + rs[2] + rs[3];
  ss = rss[0] + rss[1] + rss[2] + rss[3];
  float mean = s * (1.f / 1024.f);
  float var = ss * (1.f / 1024.f) - mean * mean;
  float rstd = rsqrtf(var + 1e-5f);
#pragma unroll
  for (int i = 0; i < 4; ++i) {
    int c = tid + i * 256;
    out[(size_t)t * 1024 + c] = (v[i] - mean) * rstd * gam[c] + bet[c];
  }
}

// ---------------- lb_loss: reduce probbuf + counts (single block) ----------------
__global__ __launch_bounds__(256) void loss_kernel(
    const float* __restrict__ probbuf, const int* __restrict__ counts,
    float* __restrict__ out) {
  __shared__ float ps[256][8];
  float a[8];
#pragma unroll
  for (int e = 0; e < 8; ++e) a[e] = 0.f;
  for (int r = threadIdx.x; r < TOK; r += 256) {
#pragma unroll
    for (int e = 0; e < 8; ++e) a[e] += probbuf[(size_t)r * 8 + e];
  }
#pragma unroll
  for (int e = 0; e < 8; ++e) ps[threadIdx.x][e] = a[e];
  __syncthreads();
  if (threadIdx.x == 0) {
    float s = 0.f;
#pragma unroll
    for (int e = 0; e < 8; ++e) {
      float imp = 0.f;
      for (int i = 0; i < 256; ++i) imp += ps[i][e];
      s += (imp * (1.f / 4096.f)) * ((float)counts[e] * (1.f / 4096.f));
    }
    out[0] = 8.f * s;
  }
}

// =========================================================================
extern "C" void kernel_launch(void* const* d_in, const int* in_sizes, int n_in,
                              void* d_out, int out_size, void* d_ws, size_t ws_size,
                              hipStream_t stream) {
  const float* x = (const float*)d_in[0];
  const int* amask = (const int*)d_in[1];
  const float* Wq = (const float*)d_in[2]; const float* bq = (const float*)d_in[3];
  const float* Wk = (const float*)d_in[4]; const float* bk = (const float*)d_in[5];
  const float* Wv = (const float*)d_in[6]; const float* bv = (const float*)d_in[7];
  const float* Wo = (const float*)d_in[8]; const float* bo = (const float*)d_in[9];
  const float* g1 = (const float*)d_in[10]; const float* be1 = (const float*)d_in[11];
  const float* g2 = (const float*)d_in[12]; const float* be2 = (const float*)d_in[13];
  const float* Wr = (const float*)d_in[14]; const float* br = (const float*)d_in[15];
  const float* W1 = (const float*)d_in[16]; const float* b1 = (const float*)d_in[17];
  const float* W2 = (const float*)d_in[18]; const float* b2 = (const float*)d_in[19];
  float* out = (float*)d_out;

  char* w = (char*)d_ws;
  auto alloc = [&](size_t bytes) -> char* {
    char* p = w; w += (bytes + 255) & ~(size_t)255; return p;
  };
  _Float16* xsh = (_Float16*)alloc((size_t)TOK * CCD * 2);
  _Float16* xsl = (_Float16*)alloc((size_t)TOK * CCD * 2);
  _Float16* wqh = (_Float16*)alloc((size_t)3072 * 1024 * 2);
  _Float16* wql = (_Float16*)alloc((size_t)3072 * 1024 * 2);
  _Float16* woh = (_Float16*)alloc((size_t)1024 * 1024 * 2);
  _Float16* wol = (_Float16*)alloc((size_t)1024 * 1024 * 2);
  _Float16* qhi = (_Float16*)alloc((size_t)TOK * CCD * 2);   // oe aliases qhi..klo (32 MB)
  _Float16* qlo = (_Float16*)alloc((size_t)TOK * CCD * 2);
  _Float16* khi = (_Float16*)alloc((size_t)TOK * CCD * 2);
  _Float16* klo = (_Float16*)alloc((size_t)TOK * CCD * 2);
  _Float16* vhi = (_Float16*)alloc((size_t)TOK * CCD * 2);
  _Float16* vlo = (_Float16*)alloc((size_t)TOK * CCD * 2);
  _Float16* vthi = (_Float16*)alloc((size_t)TOK * CCD * 2);
  _Float16* vtlo = (_Float16*)alloc((size_t)TOK * CCD * 2);
  _Float16* ohi = (_Float16*)alloc((size_t)TOK * CCD * 2);
  _Float16* olo = (_Float16*)alloc((size_t)TOK * CCD * 2);
  float* mha = (float*)alloc((size_t)TOK * CCD * 4);
  float* x1f = (float*)alloc((size_t)TOK * CCD * 4);
  u16* x1b = (u16*)alloc((size_t)TOK * CCD * 2);
  u16* w1t = (u16*)alloc((size_t)8 * HIDD * CCD * 2);
  u16* w2t = (u16*)alloc((size_t)8 * CCD * HIDD * 2);
  u16* hbuf = (u16*)alloc((size_t)8192 * HIDD * 2);
  float* probbuf = (float*)alloc((size_t)TOK * 8 * 4);
  int* eids = (int*)alloc(TOK * 2 * 4);
  float* gatesv = (float*)alloc(TOK * 2 * 4);
  int* invx = (int*)alloc(TOK * 2 * 4);
  int* tlist = (int*)alloc(8192 * 4);
  char* ctrl = alloc(4096);
  int* counts = (int*)ctrl;
  int* cursor = counts + 8;
  int* offs = counts + 16;           // 9 ints
  u16* oe = (u16*)qhi;               // 2 x 8192 x 1024 bf16 partials = 32 MB; q/k dead by FF2

  hipMemsetAsync(ctrl, 0, 256, stream);

  cast_split_kernel<<<4096, 256, 0, stream>>>(x, xsh, xsl);
  trans_split_kernel<<<dim3(32, 32), 256, 0, stream>>>(Wq, wqh, wql, 1024, 1024);
  trans_split_kernel<<<dim3(32, 32), 256, 0, stream>>>(Wk, wqh + (size_t)1024 * 1024, wql + (size_t)1024 * 1024, 1024, 1024);
  trans_split_kernel<<<dim3(32, 32), 256, 0, stream>>>(Wv, wqh + (size_t)2048 * 1024, wql + (size_t)2048 * 1024, 1024, 1024);
  trans_split_kernel<<<dim3(32, 32), 256, 0, stream>>>(Wo, woh, wol, 1024, 1024);
  trans_bf16_kernel<<<dim3(16, 128, 8), 256, 0, stream>>>(W1, w1t, 1024, 4096);
  trans_bf16_kernel<<<dim3(64, 32, 8), 256, 0, stream>>>(W2, w2t, 4096, 1024);

  gemm_f16x3_kernel<0><<<dim3(32, 24), 512, 0, stream>>>(
      xsh, xsl, wqh, wql, bq, bk, bv,
      qhi, qlo, khi, klo, vhi, vlo, nullptr, 4096, 3072, 1024);
  vtrans_kernel<<<dim3(16, 2, 64), 256, 0, stream>>>(vhi, vlo, vthi, vtlo);
  attn_kernel<<<512, 256, 0, stream>>>(qhi, qlo, khi, klo, vthi, vtlo, amask, ohi, olo);
  gemm_f16x3_kernel<1><<<dim3(32, 8), 512, 0, stream>>>(
      ohi, olo, woh, wol, bo, nullptr, nullptr,
      nullptr, nullptr, nullptr, nullptr, nullptr, nullptr, mha, 4096, 1024, 1024);
  ln1_kernel<<<4096, 256, 0, stream>>>(x, mha, g1, be1, x1f, x1b);
  router_kernel<<<1024, 256, 0, stream>>>(x1f, Wr, br, eids, gatesv, probbuf);
  count_offs_kernel<<<1, 256, 0, stream>>>(eids, counts, offs);
  scatter_kernel<<<16, 256, 0, stream>>>(eids, offs, cursor, tlist, invx);
  gemm_bf16_kernel<2><<<dim3(8 * MAXMT * 32, 1), 512, 0, stream>>>(
      x1b, w1t, b1, hbuf, nullptr, tlist, offs, 1024, 1024, 4096, 32);
  gemm_bf16_kernel<3><<<dim3(8 * MAXMT * 8, 2), 512, 0, stream>>>(
      hbuf, w2t, b2, oe, nullptr, nullptr, offs, 2048, 4096, 1024, 8);
  ln2_kernel<<<4096, 256, 0, stream>>>(x1f, oe, invx, gatesv, g2, be2, out);
  loss_kernel<<<1, 256, 0, stream>>>(probbuf, counts, out + (size_t)TOK * CCD);
}